// Round 8
// baseline (129.915 us; speedup 1.0000x reference)
//
#include <hip/hip_runtime.h>
#include <cmath>

#define BB 128
#define TT 4096
#define NN 48

typedef short bf16x8 __attribute__((ext_vector_type(8)));
typedef short bf16x4 __attribute__((ext_vector_type(4)));
typedef float f32x4 __attribute__((ext_vector_type(4)));
typedef int   i32x4 __attribute__((ext_vector_type(4)));
typedef int   i32x2 __attribute__((ext_vector_type(2)));

__device__ __forceinline__ float wave_reduce_sum(float v) {
  #pragma unroll
  for (int m = 32; m >= 1; m >>= 1) v += __shfl_xor(v, m, 64);
  return v;
}
__device__ __forceinline__ int bperm(int byteidx, int src) {
  return __builtin_amdgcn_ds_bpermute(byteidx, src);
}
__device__ __forceinline__ float lane_bcast(float x, int lane) {
  return __uint_as_float((unsigned)__builtin_amdgcn_readlane(__float_as_int(x), lane));
}
__device__ __forceinline__ int cvt_pk_bf16(float lo, float hi) {
  int r;
  asm("v_cvt_pk_bf16_f32 %0, %1, %2" : "=v"(r) : "v"(lo), "v"(hi));
  return r;
}
__device__ __forceinline__ unsigned short f2bf(float f) {  // RNE f32->bf16
  unsigned u = __float_as_uint(f);
  unsigned r = (u + 0x7FFFu + ((u >> 16) & 1u)) >> 16;
  return (unsigned short)r;
}

// ---------------- Phase 1: per-(batch,chunk) transition-matrix product ----
// One wave per (b,c). Chain Y <- diag(w_t) * E^T * Y  (Y as MFMA B-operand,
// static A = E^T/48), K-space relabel so C-words == next B-words verbatim
// (verified R4-R6, absmax 0.0).
// R7/R8: w-broadcast via PACKED bf16 PAIRS -> 6 ds_bpermute/step (was 12; DS
// pipe was ~100% busy = the R6 wall). w pipeline is double-buffered (WA/WB):
// exp+pack+bperm for step t+1 issue before step t's MFMAs, so bperm latency
// hides under the matrix chain. R8 fixes R7's bug: the PROLOGUE must pack
// exp(em[t0]), not em[t0] (that raw-value first step collapsed the product
// to 0 -> log(0) = -inf).
template<int NC, int CL>
__global__ __launch_bounds__(64) __attribute__((amdgpu_waves_per_eu(4, 4)))
void crf_chunk_kernel(const float* __restrict__ em,
                      const float* __restrict__ trans,
                      const int* __restrict__ tags,
                      unsigned short* __restrict__ G,
                      float* __restrict__ sc_part) {
  const int blk = blockIdx.x;
  const int b = blk / NC;
  const int c = blk % NC;
  const int l = threadIdx.x;
  const int g = l >> 4;
  const int rr = l & 15;
  const int jc = (l < NN) ? l : (NN - 1);
  const bool odd = (l & 1);
  const float FSCALE = 1.0f / 48.0f;

  // ---- static A = E^T/48. K-tile0 (16x16x32): label phi(g,e)=16*(e>>2)+4g+(e&3)
  //      K-tile1 (16x16x16): label psi(g,e)=32+4g+e
  bf16x8 Af0[3];
  bf16x4 Af1[3];
  #pragma unroll
  for (int mt = 0; mt < 3; ++mt) {
    const int i = 16 * mt + rr;
    bf16x8 a0;
    bf16x4 a1;
    #pragma unroll
    for (int e = 0; e < 8; ++e) {
      int k0 = 16 * (e >> 2) + 4 * g + (e & 3);
      a0[e] = (short)f2bf(__expf(trans[k0 * NN + i]) * FSCALE);
    }
    #pragma unroll
    for (int e = 0; e < 4; ++e) {
      int k1 = 32 + 4 * g + e;
      a1[e] = (short)f2bf(__expf(trans[k1 * NN + i]) * FSCALE);
    }
    Af0[mt] = a0; Af1[mt] = a1;
  }

  // ---- persistent state: Y = I in B-quad encoding.
  i32x4 B0s[3];
  i32x2 B1s[3];
  #pragma unroll
  for (int nt = 0; nt < 3; ++nt) {
    const int col = 16 * nt + rr;
    i32x4 b0;
    i32x2 b1;
    #pragma unroll
    for (int w = 0; w < 4; ++w) {
      int r0 = 16 * (w >> 1) + 4 * g + 2 * (w & 1);
      b0[w] = ((r0 == col) ? 0x3F80 : 0) | (((r0 + 1 == col) ? 0x3F80 : 0) << 16);
    }
    #pragma unroll
    for (int w = 0; w < 2; ++w) {
      int r0 = 32 + 4 * g + 2 * w;
      b1[w] = ((r0 == col) ? 0x3F80 : 0) | (((r0 + 1 == col) ? 0x3F80 : 0) << 16);
    }
    B0s[nt] = b0; B1s[nt] = b1;
  }

  const f32x4 zq = {0.f, 0.f, 0.f, 0.f};

  // bperm byte indices for the 6 w-pairs: pair(mt,h) holds rows 16mt+4g+2h,+1
  // at lane 2*(8mt+2g+h) -> byte idx 64mt+16g+8h
  const int wx0 = 16 * g;        // (mt0,h0)
  const int wx1 = 16 * g + 8;    // (mt0,h1)
  const int wx2 = 16 * g + 64;   // (mt1,h0)
  const int wx3 = 16 * g + 72;   // (mt1,h1)
  const int wx4 = 16 * g + 128;  // (mt2,h0)
  const int wx5 = 16 * g + 136;  // (mt2,h1)

  const float* embr = em + (size_t)b * TT * NN + jc;
  const int t0 = c * CL + 1;

  // 8-deep emission prefetch (named registers)
  float pf0 = embr[(size_t)(t0 + 0) * NN];
  float pf1 = embr[(size_t)(t0 + 1) * NN];
  float pf2 = embr[(size_t)(t0 + 2) * NN];
  float pf3 = embr[(size_t)(t0 + 3) * NN];
  float pf4 = embr[(size_t)(t0 + 4) * NN];
  float pf5 = embr[(size_t)(t0 + 5) * NN];
  float pf6 = embr[(size_t)(t0 + 6) * NN];
  float pf7 = embr[(size_t)(t0 + 7) * NN];

  // w-pair double buffer
  int wa0, wa1, wa2, wa3, wa4, wa5;
  int wb0, wb1, wb2, wb3, wb4, wb5;

  // pack w (f32, per-lane own row) into bf16 pairs and bperm-distribute.
  // WSRC must already be exp(em).
  #define PACKW(WSRC, d0, d1, d2, d3, d4, d5) do {                            \
    int wi_ = __float_as_int(WSRC);                                           \
    int nb_ = __builtin_amdgcn_update_dpp(wi_, wi_, 0xB1, 0xF, 0xF, true);    \
    float lo_ = odd ? __int_as_float(nb_) : (WSRC);                           \
    float hi_ = odd ? (WSRC) : __int_as_float(nb_);                           \
    int pk_ = cvt_pk_bf16(lo_, hi_);                                          \
    d0 = bperm(wx0, pk_); d1 = bperm(wx1, pk_);                               \
    d2 = bperm(wx2, pk_); d3 = bperm(wx3, pk_);                               \
    d4 = bperm(wx4, pk_); d5 = bperm(wx5, pk_);                               \
  } while (0)

  // one step: current w-pairs c0..c5; fills n0..n5 for the NEXT step from PFN.
  #define STEPX(PFN, RELOAD, c0, c1, c2, c3, c4, c5, n0, n1, n2, n3, n4, n5) do { \
    float wn_ = __expf(PFN);                                                  \
    RELOAD;                                                                   \
    PACKW(wn_, n0, n1, n2, n3, n4, n5);                                       \
    float u0_ = __int_as_float(c0 << 16), u1_ = __int_as_float(c0 & 0xFFFF0000); \
    float u2_ = __int_as_float(c1 << 16), u3_ = __int_as_float(c1 & 0xFFFF0000); \
    float u4_ = __int_as_float(c2 << 16), u5_ = __int_as_float(c2 & 0xFFFF0000); \
    float u6_ = __int_as_float(c3 << 16), u7_ = __int_as_float(c3 & 0xFFFF0000); \
    float u8_ = __int_as_float(c4 << 16), u9_ = __int_as_float(c4 & 0xFFFF0000); \
    float u10_ = __int_as_float(c5 << 16), u11_ = __int_as_float(c5 & 0xFFFF0000); \
    _Pragma("unroll") for (int nt = 0; nt < 3; ++nt) {                        \
      bf16x4 b1c_ = __builtin_bit_cast(bf16x4, B1s[nt]);                      \
      bf16x8 b0c_ = __builtin_bit_cast(bf16x8, B0s[nt]);                      \
      f32x4 a0_ = __builtin_amdgcn_mfma_f32_16x16x16bf16_1k(Af1[0], b1c_, zq, 0, 0, 0); \
      f32x4 a1_ = __builtin_amdgcn_mfma_f32_16x16x16bf16_1k(Af1[1], b1c_, zq, 0, 0, 0); \
      f32x4 a2_ = __builtin_amdgcn_mfma_f32_16x16x16bf16_1k(Af1[2], b1c_, zq, 0, 0, 0); \
      a0_ = __builtin_amdgcn_mfma_f32_16x16x32_bf16(Af0[0], b0c_, a0_, 0, 0, 0); \
      a1_ = __builtin_amdgcn_mfma_f32_16x16x32_bf16(Af0[1], b0c_, a1_, 0, 0, 0); \
      a2_ = __builtin_amdgcn_mfma_f32_16x16x32_bf16(Af0[2], b0c_, a2_, 0, 0, 0); \
      B0s[nt][0] = cvt_pk_bf16(a0_[0] * u0_,  a0_[1] * u1_);                  \
      B0s[nt][1] = cvt_pk_bf16(a0_[2] * u2_,  a0_[3] * u3_);                  \
      B0s[nt][2] = cvt_pk_bf16(a1_[0] * u4_,  a1_[1] * u5_);                  \
      B0s[nt][3] = cvt_pk_bf16(a1_[2] * u6_,  a1_[3] * u7_);                  \
      B1s[nt][0] = cvt_pk_bf16(a2_[0] * u8_,  a2_[1] * u9_);                  \
      B1s[nt][1] = cvt_pk_bf16(a2_[2] * u10_, a2_[3] * u11_);                 \
    }                                                                         \
  } while (0)

  #define RELC(PF, NT) PF = embr[(size_t)(((NT) > (TT - 1)) ? (TT - 1) : (NT)) * NN]

  // prologue: w for step t0 from pf0 (em[t0]) -- MUST be exp(em) (R7 bug fix)
  {
    float w0_ = __expf(pf0);
    PACKW(w0_, wa0, wa1, wa2, wa3, wa4, wa5);
  }

  if (c != NC - 1) {
    // CL steps; prefetch/exp may read up to 8 rows into the next chunk (in-bounds).
    const float* pref = embr + (size_t)(t0 + 8) * NN;
    #pragma unroll 1
    for (int it = 0; it < CL / 8; ++it) {
      STEPX(pf1, (pf0 = pref[0 * NN]), wa0, wa1, wa2, wa3, wa4, wa5, wb0, wb1, wb2, wb3, wb4, wb5);
      STEPX(pf2, (pf1 = pref[1 * NN]), wb0, wb1, wb2, wb3, wb4, wb5, wa0, wa1, wa2, wa3, wa4, wa5);
      STEPX(pf3, (pf2 = pref[2 * NN]), wa0, wa1, wa2, wa3, wa4, wa5, wb0, wb1, wb2, wb3, wb4, wb5);
      STEPX(pf4, (pf3 = pref[3 * NN]), wb0, wb1, wb2, wb3, wb4, wb5, wa0, wa1, wa2, wa3, wa4, wa5);
      STEPX(pf5, (pf4 = pref[4 * NN]), wa0, wa1, wa2, wa3, wa4, wa5, wb0, wb1, wb2, wb3, wb4, wb5);
      STEPX(pf6, (pf5 = pref[5 * NN]), wb0, wb1, wb2, wb3, wb4, wb5, wa0, wa1, wa2, wa3, wa4, wa5);
      STEPX(pf7, (pf6 = pref[6 * NN]), wa0, wa1, wa2, wa3, wa4, wa5, wb0, wb1, wb2, wb3, wb4, wb5);
      STEPX(pf0, (pf7 = pref[7 * NN]), wb0, wb1, wb2, wb3, wb4, wb5, wa0, wa1, wa2, wa3, wa4, wa5);
      pref += 8 * NN;
    }
  } else {
    // CL-1 steps: (CL/8 - 2) fast iterations, then 15 clamped steps.
    const float* pref = embr + (size_t)(t0 + 8) * NN;
    #pragma unroll 1
    for (int it = 0; it < CL / 8 - 2; ++it) {
      STEPX(pf1, (pf0 = pref[0 * NN]), wa0, wa1, wa2, wa3, wa4, wa5, wb0, wb1, wb2, wb3, wb4, wb5);
      STEPX(pf2, (pf1 = pref[1 * NN]), wb0, wb1, wb2, wb3, wb4, wb5, wa0, wa1, wa2, wa3, wa4, wa5);
      STEPX(pf3, (pf2 = pref[2 * NN]), wa0, wa1, wa2, wa3, wa4, wa5, wb0, wb1, wb2, wb3, wb4, wb5);
      STEPX(pf4, (pf3 = pref[3 * NN]), wb0, wb1, wb2, wb3, wb4, wb5, wa0, wa1, wa2, wa3, wa4, wa5);
      STEPX(pf5, (pf4 = pref[4 * NN]), wa0, wa1, wa2, wa3, wa4, wa5, wb0, wb1, wb2, wb3, wb4, wb5);
      STEPX(pf6, (pf5 = pref[5 * NN]), wb0, wb1, wb2, wb3, wb4, wb5, wa0, wa1, wa2, wa3, wa4, wa5);
      STEPX(pf7, (pf6 = pref[6 * NN]), wa0, wa1, wa2, wa3, wa4, wa5, wb0, wb1, wb2, wb3, wb4, wb5);
      STEPX(pf0, (pf7 = pref[7 * NN]), wb0, wb1, wb2, wb3, wb4, wb5, wa0, wa1, wa2, wa3, wa4, wa5);
      pref += 8 * NN;
    }
    const int tb = t0 + CL - 16;  // pf0..pf7 hold em rows tb..tb+7
    STEPX(pf1, RELC(pf0, tb + 8),  wa0, wa1, wa2, wa3, wa4, wa5, wb0, wb1, wb2, wb3, wb4, wb5);
    STEPX(pf2, RELC(pf1, tb + 9),  wb0, wb1, wb2, wb3, wb4, wb5, wa0, wa1, wa2, wa3, wa4, wa5);
    STEPX(pf3, RELC(pf2, tb + 10), wa0, wa1, wa2, wa3, wa4, wa5, wb0, wb1, wb2, wb3, wb4, wb5);
    STEPX(pf4, RELC(pf3, tb + 11), wb0, wb1, wb2, wb3, wb4, wb5, wa0, wa1, wa2, wa3, wa4, wa5);
    STEPX(pf5, RELC(pf4, tb + 12), wa0, wa1, wa2, wa3, wa4, wa5, wb0, wb1, wb2, wb3, wb4, wb5);
    STEPX(pf6, RELC(pf5, tb + 13), wb0, wb1, wb2, wb3, wb4, wb5, wa0, wa1, wa2, wa3, wa4, wa5);
    STEPX(pf7, RELC(pf6, tb + 14), wa0, wa1, wa2, wa3, wa4, wa5, wb0, wb1, wb2, wb3, wb4, wb5);
    STEPX(pf0, RELC(pf7, tb + 15), wb0, wb1, wb2, wb3, wb4, wb5, wa0, wa1, wa2, wa3, wa4, wa5);
    STEPX(pf1, RELC(pf0, tb + 16), wa0, wa1, wa2, wa3, wa4, wa5, wb0, wb1, wb2, wb3, wb4, wb5);
    STEPX(pf2, RELC(pf1, tb + 17), wb0, wb1, wb2, wb3, wb4, wb5, wa0, wa1, wa2, wa3, wa4, wa5);
    STEPX(pf3, RELC(pf2, tb + 18), wa0, wa1, wa2, wa3, wa4, wa5, wb0, wb1, wb2, wb3, wb4, wb5);
    STEPX(pf4, RELC(pf3, tb + 19), wb0, wb1, wb2, wb3, wb4, wb5, wa0, wa1, wa2, wa3, wa4, wa5);
    STEPX(pf5, RELC(pf4, tb + 20), wa0, wa1, wa2, wa3, wa4, wa5, wb0, wb1, wb2, wb3, wb4, wb5);
    STEPX(pf6, RELC(pf5, tb + 21), wb0, wb1, wb2, wb3, wb4, wb5, wa0, wa1, wa2, wa3, wa4, wa5);
    STEPX(pf7, RELC(pf6, tb + 22), wa0, wa1, wa2, wa3, wa4, wa5, wb0, wb1, wb2, wb3, wb4, wb5);
  }
  #undef STEPX
  #undef PACKW
  #undef RELC

  // ---- store G[i][j] = Y[j][i], row-major bf16 [48][48]; j-pairs contiguous
  unsigned short* Gc = G + (size_t)blk * (NN * NN);
  #pragma unroll
  for (int nt = 0; nt < 3; ++nt) {
    const int rowoff = (16 * nt + rr) * NN + 4 * g;
    i32x2 d0; d0[0] = B0s[nt][0]; d0[1] = B0s[nt][1];
    i32x2 d1; d1[0] = B0s[nt][2]; d1[1] = B0s[nt][3];
    i32x2 d2; d2[0] = B1s[nt][0]; d2[1] = B1s[nt][1];
    *(i32x2*)(Gc + rowoff)      = d0;
    *(i32x2*)(Gc + rowoff + 16) = d1;
    *(i32x2*)(Gc + rowoff + 32) = d2;
  }

  // ---- gold-score partial for seq slice [c*TT/NC, (c+1)*TT/NC)
  const int* tgb = tags + (size_t)b * TT;
  const float* emb = em + (size_t)b * TT * NN;
  float sc = 0.0f;
  const int base = c * (TT / NC);
  #pragma unroll
  for (int q = 0; q < TT / NC; q += 64) {
    int tt = base + q + l;
    int tg = tgb[tt];
    sc += emb[(size_t)tt * NN + tg];
    if (tt > 0) sc += trans[tgb[tt - 1] * NN + tg];
  }
  sc = wave_reduce_sum(sc);
  if (l == 0) sc_part[blk] = sc;
}

// ---------------- Phase 2: combine chunk products + finalize ------------
template<int NC>
__launch_bounds__(64, 1)
__global__ void crf_combine_kernel(const float* __restrict__ em,
                                   const float* __restrict__ startv,
                                   const float* __restrict__ endv,
                                   const int* __restrict__ tags,
                                   const unsigned short* __restrict__ G,
                                   const float* __restrict__ sc_part,
                                   float* __restrict__ out) {
  const int b = blockIdx.x;
  const int l = threadIdx.x;
  const int jc = (l < NN) ? l : (NN - 1);
  const float* emb = em + (size_t)b * TT * NN;
  const float FSCALE = 1.0f / 48.0f;

  float r = __expf(startv[jc] + emb[jc]);

  #pragma unroll 1
  for (int c = 0; c < NC; ++c) {
    const unsigned short* Gc = G + (size_t)(b * NC + c) * (NN * NN);
    float s0 = 0.f, s1 = 0.f, s2 = 0.f, s3 = 0.f;
    #pragma unroll
    for (int i = 0; i < NN; i += 4) {
      float g0 = __uint_as_float(((unsigned)Gc[(i + 0) * NN + jc]) << 16);
      float g1 = __uint_as_float(((unsigned)Gc[(i + 1) * NN + jc]) << 16);
      float g2 = __uint_as_float(((unsigned)Gc[(i + 2) * NN + jc]) << 16);
      float g3 = __uint_as_float(((unsigned)Gc[(i + 3) * NN + jc]) << 16);
      s0 = fmaf(lane_bcast(r, i + 0), g0, s0);
      s1 = fmaf(lane_bcast(r, i + 1), g1, s1);
      s2 = fmaf(lane_bcast(r, i + 2), g2, s2);
      s3 = fmaf(lane_bcast(r, i + 3), g3, s3);
    }
    r = (s0 + s1) + (s2 + s3);
  }

  float S = wave_reduce_sum((l < NN) ? r * __expf(endv[jc]) : 0.0f);
  float scp = wave_reduce_sum((l < NC) ? sc_part[b * NC + l] : 0.0f);

  if (l == 0) {
    const int* tgb = tags + (size_t)b * TT;
    double K = -log((double)FSCALE);  // exact -ln(float(1/48))
    double logZ = log((double)S) + 4095.0 * K;
    double score = (double)scp + (double)startv[tgb[0]] + (double)endv[tgb[TT - 1]];
    out[b] = (float)(logZ - score);
  }
}

extern "C" void kernel_launch(void* const* d_in, const int* in_sizes, int n_in,
                              void* d_out, int out_size, void* d_ws, size_t ws_size,
                              hipStream_t stream) {
  const float* em     = (const float*)d_in[0];
  const float* trans  = (const float*)d_in[1];
  const float* startv = (const float*)d_in[2];
  const float* endv   = (const float*)d_in[3];
  const int*   tags   = (const int*)d_in[4];
  float* out = (float*)d_out;

  // ws: [G: BB*NC*48*48 bf16][sc_part: BB*NC f32]
  const size_t need32 = (size_t)BB * 32 * NN * NN * 2 + (size_t)BB * 32 * 4;
  if (ws_size >= need32) {
    constexpr int NC = 32, CL = TT / 32;
    unsigned short* G = (unsigned short*)d_ws;
    float* sc_part = (float*)((char*)d_ws + (size_t)BB * NC * NN * NN * 2);
    hipLaunchKernelGGL((crf_chunk_kernel<NC, CL>), dim3(BB * NC), dim3(64), 0, stream,
                       em, trans, tags, G, sc_part);
    hipLaunchKernelGGL((crf_combine_kernel<NC>), dim3(BB), dim3(64), 0, stream,
                       em, startv, endv, tags, G, sc_part, out);
  } else {
    constexpr int NC = 16, CL = TT / 16;
    unsigned short* G = (unsigned short*)d_ws;
    float* sc_part = (float*)((char*)d_ws + (size_t)BB * NC * NN * NN * 2);
    hipLaunchKernelGGL((crf_chunk_kernel<NC, CL>), dim3(BB * NC), dim3(64), 0, stream,
                       em, trans, tags, G, sc_part);
    hipLaunchKernelGGL((crf_combine_kernel<NC>), dim3(BB), dim3(64), 0, stream,
                       em, startv, endv, tags, G, sc_part, out);
  }
}